// Round 1
// baseline (24858.380 us; speedup 1.0000x reference)
//
#include <hip/hip_runtime.h>
#include <math.h>

#define NN 1000
#define INF_ 32
#define H 128
#define M 128
#define DEG 16
#define PP 2
#define OUTF 10
#define MAXM (10 * NN)        // scan length; head <= MAXM
#define QCAP (MAXM + DEG)     // only entries < MAXM are ever read

// ws layout (floats): feats[NN*H] | final[NN*H] | qm[QCAP*M]

__global__ __launch_bounds__(128)
void init_kernel(const float* __restrict__ xa, const float* __restrict__ fm,
                 const float* __restrict__ enc_w, const float* __restrict__ enc_b,
                 const int* __restrict__ nstart_p,
                 float* __restrict__ feats, float* __restrict__ finalv,
                 float* __restrict__ qm) {
    int b = blockIdx.x, t = threadIdx.x;
    float acc = enc_b[t];
    const float* xr = xa + b * INF_;
#pragma unroll
    for (int k = 0; k < INF_; ++k) acc += xr[k] * enc_w[k * H + t];
    feats[b * H + t] = acc;
    finalv[b * H + t] = 0.0f;           // ws is poisoned 0xAA each launch
    if (b < nstart_p[0]) qm[(size_t)b * M + t] = fm[b * M + t];
}

__global__ __launch_bounds__(256)
void seq_kernel(const int* __restrict__ neighbors,
                const float* __restrict__ ns_w, const float* __restrict__ ns_b,
                const float* __restrict__ nm_w, const float* __restrict__ nm_b,
                const float* __restrict__ act_w, const float* __restrict__ act_b,
                const float* __restrict__ dec_w, const float* __restrict__ dec_b,
                const int* __restrict__ nstart_p,
                float* __restrict__ feats, float* __restrict__ finalv,
                float* __restrict__ qm, float* __restrict__ out) {
    __shared__ int   s_qn[QCAP];        // 40064 B — queue node ids in LDS
    __shared__ float s_tact[NN];        // 4000 B  — per-node halting accumulator
    __shared__ float s_x[H + M];
    __shared__ float s_ns[H];
    __shared__ float s_nm[M];
    __shared__ float s_actw[H + M];
    __shared__ float s_nsb[H];
    __shared__ float s_nmb[M];
    __shared__ float s_red[4];
    __shared__ float s_g[H];
    __shared__ float s_lg[PP * OUTF];

    const int t = threadIdx.x;
    const int lane = t & 63, wid = t >> 6;
    const int nstart = nstart_p[0];

    for (int i = t; i < NN; i += 256) s_tact[i] = 0.0f;
    for (int i = t; i < nstart; i += 256) s_qn[i] = i;
    s_actw[t] = act_w[t];
    if (t < H) { s_nsb[t] = ns_b[t]; s_nmb[t] = nm_b[t]; }
    const float actb = act_b[0];
    __syncthreads();

    int head = 0, tail = nstart;
    for (int step = 0; step < MAXM; ++step) {
        if (head >= tail) break;                 // once empty, stays empty
        const int node = s_qn[head];             // uniform broadcast read
        const float ta = s_tact[node];
        if (ta <= 1.0f - 1e-7f) {                // proc (uniform branch)
            // x = concat(feats[node], qm[head])
            if (t < H) s_x[t] = feats[node * H + t];
            else       s_x[t] = qm[(size_t)head * M + (t - H)];
            __syncthreads();
            // act gate: dot(x, act_w) via shuffle + LDS reduce
            float p = s_x[t] * s_actw[t];
#pragma unroll
            for (int off = 32; off > 0; off >>= 1) p += __shfl_down(p, off, 64);
            if (lane == 0) s_red[wid] = p;
            __syncthreads();
            const float z = s_red[0] + s_red[1] + s_red[2] + s_red[3] + actb;
            const float cand = 1.0f / (1.0f + expf(-z));
            const float new_act = (ta + cand > 1.0f) ? (1.0f - ta) : cand;

            float acc;
            if (t < H) {
                // ns[t] = relu(dot256(x, ns_w[:,t]) + ns_b[t])
                float a0 = 0, a1 = 0, a2 = 0, a3 = 0;
                const float* w = ns_w + t;
#pragma unroll 4
                for (int k = 0; k < H + M; k += 4) {
                    a0 += s_x[k + 0] * w[(k + 0) * H];
                    a1 += s_x[k + 1] * w[(k + 1) * H];
                    a2 += s_x[k + 2] * w[(k + 2) * H];
                    a3 += s_x[k + 3] * w[(k + 3) * H];
                }
                acc = fmaxf(s_nsb[t] + ((a0 + a1) + (a2 + a3)), 0.0f);
                s_ns[t] = acc;
            } else {
                // msg-half of nm (independent of ns) computed concurrently
                const int j = t - H;
                const float* w = nm_w + (size_t)H * M + j;
                float a0 = 0, a1 = 0, a2 = 0, a3 = 0;
#pragma unroll 4
                for (int k = 0; k < M; k += 4) {
                    a0 += s_x[H + k + 0] * w[(k + 0) * M];
                    a1 += s_x[H + k + 1] * w[(k + 1) * M];
                    a2 += s_x[H + k + 2] * w[(k + 2) * M];
                    a3 += s_x[H + k + 3] * w[(k + 3) * M];
                }
                acc = s_nmb[j] + ((a0 + a1) + (a2 + a3));
            }
            __syncthreads();
            if (t >= H) {
                // finish nm with the ns-half
                const int j = t - H;
                const float* w = nm_w + j;
                float a0 = 0, a1 = 0, a2 = 0, a3 = 0;
#pragma unroll 4
                for (int k = 0; k < H; k += 4) {
                    a0 += s_ns[k + 0] * w[(k + 0) * M];
                    a1 += s_ns[k + 1] * w[(k + 1) * M];
                    a2 += s_ns[k + 2] * w[(k + 2) * M];
                    a3 += s_ns[k + 3] * w[(k + 3) * M];
                }
                s_nm[j] = acc + ((a0 + a1) + (a2 + a3));
            } else {
                const float nv = s_ns[t];
                feats[node * H + t] = nv;
                finalv[node * H + t] += nv * new_act;
            }
            if (t == 0) s_tact[node] = ta + new_act;
            __syncthreads();
            // enqueue DEG neighbor messages (writes past QCAP never read)
            if (t < DEG) {
                const int q = tail + t;
                if (q < QCAP) s_qn[q] = neighbors[node * DEG + t];
            }
            {
                const int col = t & (M - 1);
                for (int r = (t >> 7); r < DEG; r += 2) {
                    const int q = tail + r;
                    if (q < QCAP) qm[(size_t)q * M + col] = s_nm[col];
                }
            }
            tail += DEG;
            __syncthreads();   // s_qn/s_tact/qm visible before next pop
        }
        head += 1;
    }

    // readout: g = colsum(final); logits = g @ dec_w + dec_b; log_softmax
    __syncthreads();
    if (t < H) {
        float g0 = 0, g1 = 0, g2 = 0, g3 = 0;
        for (int n = 0; n < NN; n += 4) {
            g0 += finalv[(n + 0) * H + t];
            g1 += finalv[(n + 1) * H + t];
            g2 += finalv[(n + 2) * H + t];
            g3 += finalv[(n + 3) * H + t];
        }
        s_g[t] = (g0 + g1) + (g2 + g3);
    }
    __syncthreads();
    if (t < PP * OUTF) {
        const int pp = t / OUTF, o = t % OUTF;
        float acc = dec_b[pp * OUTF + o];
        for (int h = 0; h < H; ++h) acc += s_g[h] * dec_w[(pp * H + h) * OUTF + o];
        s_lg[t] = acc;
    }
    __syncthreads();
    if (t < PP * OUTF) {
        const int pp = t / OUTF;
        float mx = -INFINITY;
        for (int o = 0; o < OUTF; ++o) mx = fmaxf(mx, s_lg[pp * OUTF + o]);
        float s = 0.0f;
        for (int o = 0; o < OUTF; ++o) s += expf(s_lg[pp * OUTF + o] - mx);
        out[t] = s_lg[t] - (mx + logf(s));
    }
}

extern "C" void kernel_launch(void* const* d_in, const int* in_sizes, int n_in,
                              void* d_out, int out_size, void* d_ws, size_t ws_size,
                              hipStream_t stream) {
    const float* xa        = (const float*)d_in[0];
    const float* fm        = (const float*)d_in[1];
    const int*   neighbors = (const int*)  d_in[2];
    const int*   nstart_p  = (const int*)  d_in[3];
    const float* enc_w     = (const float*)d_in[4];
    const float* enc_b     = (const float*)d_in[5];
    const float* ns_w      = (const float*)d_in[6];
    const float* ns_b      = (const float*)d_in[7];
    const float* nm_w      = (const float*)d_in[8];
    const float* nm_b      = (const float*)d_in[9];
    const float* act_w     = (const float*)d_in[10];
    const float* act_b     = (const float*)d_in[11];
    const float* dec_w     = (const float*)d_in[12];
    const float* dec_b     = (const float*)d_in[13];
    float* out = (float*)d_out;

    float* feats  = (float*)d_ws;
    float* finalv = feats + NN * H;
    float* qm     = finalv + NN * H;   // QCAP*M floats ≈ 5.1 MB

    init_kernel<<<NN, 128, 0, stream>>>(xa, fm, enc_w, enc_b, nstart_p,
                                        feats, finalv, qm);
    seq_kernel<<<1, 256, 0, stream>>>(neighbors, ns_w, ns_b, nm_w, nm_b,
                                      act_w, act_b, dec_w, dec_b, nstart_p,
                                      feats, finalv, qm, out);
}